// Round 1
// baseline (782.144 us; speedup 1.0000x reference)
//
#include <hip/hip_runtime.h>
#include <stdint.h>

#define Bb 8
#define Ss 4096
#define Dd 1024
#define Mm (Bb*Ss)      // 32768 rows
#define Kk 1024

typedef _Float16 half8 __attribute__((ext_vector_type(8)));
typedef _Float16 half4v __attribute__((ext_vector_type(4)));
typedef float f32x4 __attribute__((ext_vector_type(4)));

#define LO_SCALE 2048.0f
#define INV_LO_SCALE (1.0f/2048.0f)

__device__ __forceinline__ void gld_lds16(const void* g, void* l) {
  __builtin_amdgcn_global_load_lds(
      (const __attribute__((address_space(1))) unsigned int*)g,
      (__attribute__((address_space(3))) unsigned int*)l, 16, 0, 0);
}

// ---------------- split for G(sum of 4 partials) / Wq / Wk -------------------
// G2 layout: [1024 rows][hi 1024 | lo 1024] halfs (interleaved hi/lo per row
// so the dot kernel's 8-slot XOR swizzle addresses one buffer).
__global__ void split_w3(const float* __restrict__ Gp, const float* __restrict__ Wq,
                         const float* __restrict__ Wk,
                         _Float16* __restrict__ G2, _Float16* __restrict__ Wh) {
  const int which = blockIdx.y;
  const int i = blockIdx.x * 256 + threadIdx.x;   // < Dd*Dd/4
  float4 v;
  if (which == 0) {
    float4 v0 = ((const float4*)Gp)[i];
    float4 v1 = ((const float4*)(Gp + (size_t)Dd * Dd))[i];
    float4 v2 = ((const float4*)(Gp + (size_t)2 * Dd * Dd))[i];
    float4 v3 = ((const float4*)(Gp + (size_t)3 * Dd * Dd))[i];
    v.x = (v0.x + v1.x) + (v2.x + v3.x);
    v.y = (v0.y + v1.y) + (v2.y + v3.y);
    v.z = (v0.z + v1.z) + (v2.z + v3.z);
    v.w = (v0.w + v1.w) + (v2.w + v3.w);
  } else {
    const float* src = (which == 1) ? Wq : Wk;
    v = ((const float4*)src)[i];
  }
  _Float16 h0 = (_Float16)v.x, h1 = (_Float16)v.y, h2 = (_Float16)v.z, h3 = (_Float16)v.w;
  if (which == 0) {
    _Float16 l0 = (_Float16)((v.x - (float)h0) * LO_SCALE);
    _Float16 l1 = (_Float16)((v.y - (float)h1) * LO_SCALE);
    _Float16 l2 = (_Float16)((v.z - (float)h2) * LO_SCALE);
    _Float16 l3 = (_Float16)((v.w - (float)h3) * LO_SCALE);
    const int n = i >> 8, c = i & 255;           // row, float4-col
    ((half4v*)G2)[(size_t)n * 512 + c]       = (half4v){h0, h1, h2, h3};
    ((half4v*)G2)[(size_t)n * 512 + 256 + c] = (half4v){l0, l1, l2, l3};
  } else {
    _Float16* hi = (which == 1) ? Wh : Wh + (size_t)Dd * Dd;
    ((half4v*)hi)[i] = (half4v){h0, h1, h2, h3};
  }
}

// ------- X split (wave/row) + a_u = u.x, a_v = v.x (u,v summed from partials)
// X2 layout: [32768 rows][hi 1024 | lo 1024] halfs.
__global__ void split_x(const float* __restrict__ X, const float* __restrict__ up,
                        const float* __restrict__ vp,
                        _Float16* __restrict__ X2,
                        float* __restrict__ a_u, float* __restrict__ a_v) {
  const int s = blockIdx.x * 4 + (threadIdx.x >> 6);
  const int lane = threadIdx.x & 63;
  float au = 0.f, av = 0.f;
#pragma unroll
  for (int c = 0; c < 4; ++c) {
    const int e = c * 256 + lane * 4;
    float4 xv = *(const float4*)&X[(size_t)s * Dd + e];
    float4 uv = {0.f, 0.f, 0.f, 0.f}, vv = {0.f, 0.f, 0.f, 0.f};
#pragma unroll
    for (int z = 0; z < 4; ++z) {
      float4 a = *(const float4*)&up[(size_t)z * Dd + e];
      float4 b = *(const float4*)&vp[(size_t)z * Dd + e];
      uv.x += a.x; uv.y += a.y; uv.z += a.z; uv.w += a.w;
      vv.x += b.x; vv.y += b.y; vv.z += b.z; vv.w += b.w;
    }
    _Float16 h0 = (_Float16)xv.x, h1 = (_Float16)xv.y, h2 = (_Float16)xv.z, h3 = (_Float16)xv.w;
    _Float16 l0 = (_Float16)((xv.x - (float)h0) * LO_SCALE);
    _Float16 l1 = (_Float16)((xv.y - (float)h1) * LO_SCALE);
    _Float16 l2 = (_Float16)((xv.z - (float)h2) * LO_SCALE);
    _Float16 l3 = (_Float16)((xv.w - (float)h3) * LO_SCALE);
    *(half4v*)&X2[(size_t)s * 2048 + e]        = (half4v){h0, h1, h2, h3};
    *(half4v*)&X2[(size_t)s * 2048 + 1024 + e] = (half4v){l0, l1, l2, l3};
    au += uv.x * xv.x + uv.y * xv.y + uv.z * xv.z + uv.w * xv.w;
    av += vv.x * xv.x + vv.y * xv.y + vv.z * xv.z + vv.w * xv.w;
  }
#pragma unroll
  for (int off = 32; off > 0; off >>= 1) {
    au += __shfl_xor(au, off);
    av += __shfl_xor(av, off);
  }
  if (lane == 0) { a_u[s] = au; a_v[s] = av; }
}

// ------- G partial: Gp[z] = Wq[kz]^T * Wk[kz], K-split x4 ---------------------
__global__ __launch_bounds__(256)
void gemm_g_part(const float* __restrict__ Wq, const float* __restrict__ Wk,
                 float* __restrict__ Gp) {
  __shared__ float As[16][64];
  __shared__ float Bs[16][64];
  const int t = threadIdx.x;
  const int m0 = blockIdx.y * 64, n0 = blockIdx.x * 64;
  const int kbase = blockIdx.z * 256;
  float acc[4][4];
#pragma unroll
  for (int a = 0; a < 4; ++a)
#pragma unroll
    for (int b = 0; b < 4; ++b) acc[a][b] = 0.f;
  for (int kc = 0; kc < 16; ++kc) {
    const int k0 = kbase + kc * 16;
#pragma unroll
    for (int l = 0; l < 4; ++l) {
      const int idx = l * 256 + t;
      const int kk = idx >> 6, mm = idx & 63;
      As[kk][mm] = Wq[(size_t)(k0 + kk) * Dd + m0 + mm];
      Bs[kk][mm] = Wk[(size_t)(k0 + kk) * Dd + n0 + mm];
    }
    __syncthreads();
    const int tm = (t & 15) * 4, tn = (t >> 4) * 4;
#pragma unroll
    for (int k = 0; k < 16; ++k) {
      float4 a4 = *(const float4*)&As[k][tm];
      float4 b4 = *(const float4*)&Bs[k][tn];
      const float aa[4] = {a4.x, a4.y, a4.z, a4.w};
      const float bb[4] = {b4.x, b4.y, b4.z, b4.w};
#pragma unroll
      for (int a = 0; a < 4; ++a)
#pragma unroll
        for (int b = 0; b < 4; ++b) acc[a][b] += aa[a] * bb[b];
    }
    __syncthreads();
  }
  float* dst = Gp + (size_t)blockIdx.z * Dd * Dd;
  const int tm = (t & 15) * 4, tn = (t >> 4) * 4;
#pragma unroll
  for (int a = 0; a < 4; ++a)
#pragma unroll
    for (int b = 0; b < 4; ++b)
      dst[(size_t)(m0 + tm + a) * Dd + n0 + tn + b] = acc[a][b];
}

// ------- u/v partials over e-chunks (32 blocks) + c (block 32) ---------------
__global__ void uvc_part(const float* __restrict__ Wq, const float* __restrict__ Wk,
                         const float* __restrict__ bq, const float* __restrict__ bk,
                         float* __restrict__ up, float* __restrict__ vp,
                         float* __restrict__ c) {
  const int bx = blockIdx.x;
  if (bx == 32) {
    const int lane = threadIdx.x;
    if (lane >= 64) return;
    float a = 0.f;
#pragma unroll
    for (int i = 0; i < 16; ++i) a += bq[lane * 16 + i] * bk[lane * 16 + i];
#pragma unroll
    for (int off = 32; off > 0; off >>= 1) a += __shfl_xor(a, off);
    if (lane == 0) *c = a;
    return;
  }
  const int echunk = bx & 3;
  const int which = (bx >> 2) & 1;   // 0 -> u (bq.Wk), 1 -> v (bk.Wq)
  const int dchunk = bx >> 3;
  const int d = dchunk * 256 + threadIdx.x;
  const float* W = which ? Wq : Wk;
  const float* bb = which ? bk : bq;
  float acc = 0.f;
  const int e0 = echunk * 256;
#pragma unroll 4
  for (int e = e0; e < e0 + 256; ++e) acc += bb[e] * W[(size_t)e * Dd + d];
  float* dst = which ? vp : up;
  dst[(size_t)echunk * Dd + d] = acc;
}

// =====================  pipelined MFMA GEMMs  ================================
// BM=256, BN=128, 512 thr (8 waves: 2 M-groups x 4 N-groups; per-wave 128x32).
// Triple-buffered LDS (3 x 48KB = 144KB), counted s_waitcnt vmcnt(6): loads for
// K-tile t+2 are issued right after tile t's raw s_barrier and stay in flight
// across two barriers — the main loop never drains vmcnt to 0 (T3+T4).
// Slot discipline: iter t reads slot t%3; iter t issues t+2 into (t+2)%3 ==
// (t-1)%3, legal because the barrier guarantees all waves finished tile t-1.
// All waves vmcnt-wait *before* the barrier => tile t fully in LDS after it.
// LDS rows are 128B / 8 slots with the proven XOR-8 swizzle (bank-conflict 0).

// ---------------- dot GEMM: (X2 hi/lo) x (G2 hi/lo)^T, BK=32 -----------------
// row layout [hi0..hi3 | lo0..lo3] x 8-half slots; slot u = (h*4+g) ^ (R&7).
__global__ __launch_bounds__(512, 2)
void gemm_dot(const _Float16* __restrict__ X2, const _Float16* __restrict__ G2,
              const float* __restrict__ X, float* __restrict__ pd) {
  __shared__ __align__(16) _Float16 smem[3 * 24576];   // 144 KB
  const int tid = threadIdx.x;
  const int wave = tid >> 6, lane = tid & 63;
  // XCD-chunked swizzle: 1024 wgs, 8 XCDs -> XCD c owns logical [c*128,c*128+128)
  // => the 8 col-blocks of an A-panel run on one XCD (G2 = 4MB = one L2).
  const int lin = blockIdx.y * 8 + blockIdx.x;
  const int logical = (lin & 7) * 128 + (lin >> 3);
  const int n0 = (logical & 7) * 128;
  const int m0 = (logical >> 3) * 256;
  const int wm = (wave >> 2) * 128;
  const int wn = (wave & 3) * 32;
  const int fr = lane & 15, g4 = lane >> 4;
  const int sr = lane >> 3, sc = lane & 7;

  // staging sources (pre-swizzled global address, linear LDS dest)
  size_t aoff[4];
  size_t boff[2];
#pragma unroll
  for (int st = 0; st < 4; ++st) {
    const int R = st * 64 + wave * 8 + sr;
    const int u = sc ^ (R & 7);
    aoff[st] = (size_t)(m0 + R) * 2048 + ((u & 3) << 3) + ((size_t)(u >> 2) << 10);
  }
#pragma unroll
  for (int st = 0; st < 2; ++st) {
    const int R = st * 64 + wave * 8 + sr;
    const int u = sc ^ (R & 7);
    boff[st] = (size_t)(n0 + R) * 2048 + ((u & 3) << 3) + ((size_t)(u >> 2) << 10);
  }
  // fragment read offsets (halfs), invariant across K-tiles
  int aro[2][8], bro[2][2];
#pragma unroll
  for (int i = 0; i < 8; ++i) {
    const int Ra = wm + i * 16 + fr;
    aro[0][i] = Ra * 64 + ((g4 ^ (Ra & 7)) << 3);
    aro[1][i] = Ra * 64 + (((4 | g4) ^ (Ra & 7)) << 3);
  }
#pragma unroll
  for (int j = 0; j < 2; ++j) {
    const int Rb = wn + j * 16 + fr;
    bro[0][j] = Rb * 64 + ((g4 ^ (Rb & 7)) << 3);
    bro[1][j] = Rb * 64 + (((4 | g4) ^ (Rb & 7)) << 3);
  }

  f32x4 accH[8][2], accX[8][2];
#pragma unroll
  for (int i = 0; i < 8; ++i)
#pragma unroll
    for (int j = 0; j < 2; ++j) {
      accH[i][j] = (f32x4){0.f, 0.f, 0.f, 0.f};
      accX[i][j] = (f32x4){0.f, 0.f, 0.f, 0.f};
    }

#define DOT_STAGE(kt, slot) do {                                      \
    const size_t kof = (size_t)(kt) * 32;                             \
    _Float16* sb_ = smem + (slot) * 24576;                            \
    gld_lds16(X2 + aoff[0] + kof, sb_ + 0 * 4096 + wave * 512);       \
    gld_lds16(X2 + aoff[1] + kof, sb_ + 1 * 4096 + wave * 512);       \
    gld_lds16(X2 + aoff[2] + kof, sb_ + 2 * 4096 + wave * 512);       \
    gld_lds16(X2 + aoff[3] + kof, sb_ + 3 * 4096 + wave * 512);       \
    gld_lds16(G2 + boff[0] + kof, sb_ + 16384 + 0 * 4096 + wave * 512); \
    gld_lds16(G2 + boff[1] + kof, sb_ + 16384 + 1 * 4096 + wave * 512); \
  } while (0)

  DOT_STAGE(0, 0);
  DOT_STAGE(1, 1);
  int slot = 0;
  for (int kt = 0; kt < 32; ++kt) {
    // own 6 loads of tile kt must land; tile kt+1's 6 may stay in flight
    if (kt < 31) asm volatile("s_waitcnt vmcnt(6)" ::: "memory");
    else         asm volatile("s_waitcnt vmcnt(0)" ::: "memory");
    __builtin_amdgcn_s_barrier();      // raw: no vmcnt(0) drain
    asm volatile("" ::: "memory");
    if (kt + 2 < 32) {
      int s2 = slot + 2; if (s2 >= 3) s2 -= 3;
      DOT_STAGE(kt + 2, s2);
    }
    const _Float16* A  = smem + slot * 24576;
    const _Float16* Bm = A + 16384;
    half8 bh[2], bl[2];
#pragma unroll
    for (int j = 0; j < 2; ++j) {
      bh[j] = *(const half8*)&Bm[bro[0][j]];
      bl[j] = *(const half8*)&Bm[bro[1][j]];
    }
#pragma unroll
    for (int ph = 0; ph < 4; ++ph) {
      const int i0 = ph * 2;
      half8 ah0 = *(const half8*)&A[aro[0][i0]];
      half8 al0 = *(const half8*)&A[aro[1][i0]];
      half8 ah1 = *(const half8*)&A[aro[0][i0 + 1]];
      half8 al1 = *(const half8*)&A[aro[1][i0 + 1]];
      __builtin_amdgcn_s_setprio(1);
#pragma unroll
      for (int j = 0; j < 2; ++j) {
        accH[i0][j]     = __builtin_amdgcn_mfma_f32_16x16x32_f16(ah0, bh[j], accH[i0][j], 0, 0, 0);
        accX[i0][j]     = __builtin_amdgcn_mfma_f32_16x16x32_f16(ah0, bl[j], accX[i0][j], 0, 0, 0);
        accX[i0][j]     = __builtin_amdgcn_mfma_f32_16x16x32_f16(al0, bh[j], accX[i0][j], 0, 0, 0);
        accH[i0 + 1][j] = __builtin_amdgcn_mfma_f32_16x16x32_f16(ah1, bh[j], accH[i0 + 1][j], 0, 0, 0);
        accX[i0 + 1][j] = __builtin_amdgcn_mfma_f32_16x16x32_f16(ah1, bl[j], accX[i0 + 1][j], 0, 0, 0);
        accX[i0 + 1][j] = __builtin_amdgcn_mfma_f32_16x16x32_f16(al1, bh[j], accX[i0 + 1][j], 0, 0, 0);
      }
      __builtin_amdgcn_s_setprio(0);
    }
    __builtin_amdgcn_sched_barrier(0);  // pin MFMAs before next barrier (rule 18)
    slot = (slot == 2) ? 0 : slot + 1;
  }

  // epilogue: d_t += x_t . y_{t-1} over this block's 128 cols, then block-reduce
  // the 4 N-wave-group partials through LDS -> one pd slot per col-block.
  float* scratch = (float*)smem;       // [256][4]; slot 0 region, disjoint from slot 1
  const int quad = g4;
#pragma unroll
  for (int i = 0; i < 8; ++i) {
#pragma unroll
    for (int r = 0; r < 4; ++r) {
      const int row = wm + 16 * i + quad * 4 + r;
      const int t = m0 + row + 1;
      float dsum = 0.f;
      if ((t & (Ss - 1)) != 0) {
        const float* xrow = X + (size_t)t * Dd + n0 + wn;
#pragma unroll
        for (int j = 0; j < 2; ++j) {
          float yv = accH[i][j][r] + accX[i][j][r] * INV_LO_SCALE;
          dsum += yv * xrow[16 * j + fr];
        }
      }
      dsum += __shfl_xor(dsum, 1);
      dsum += __shfl_xor(dsum, 2);
      dsum += __shfl_xor(dsum, 4);
      dsum += __shfl_xor(dsum, 8);
      if (fr == 0) scratch[row * 4 + (wave & 3)] = dsum;
    }
  }
  __syncthreads();
  if (tid < 256) {
    const int t = m0 + tid + 1;
    if ((t & (Ss - 1)) != 0) {
      float v = scratch[tid * 4] + scratch[tid * 4 + 1] +
                scratch[tid * 4 + 2] + scratch[tid * 4 + 3];
      pd[(size_t)(logical & 7) * Mm + t] = v;
    }
  }
}

// ---------------- norm GEMM: Xh x [Wq;Wk]^T (hi only), BK=64 -----------------
__global__ __launch_bounds__(512, 2)
void gemm_norm(const _Float16* __restrict__ X2, const _Float16* __restrict__ Wh,
               const float* __restrict__ bq, const float* __restrict__ bk,
               float* __restrict__ pn) {
  __shared__ __align__(16) _Float16 smem[3 * 24576];   // 144 KB
  const int tid = threadIdx.x;
  const int wave = tid >> 6, lane = tid & 63;
  const int lin = blockIdx.y * 16 + blockIdx.x;        // 2048 wgs
  const int logical = (lin & 7) * 256 + (lin >> 3);
  const int n0 = (logical & 15) * 128;
  const int m0 = (logical >> 4) * 256;
  const int wm = (wave >> 2) * 128;
  const int wn = (wave & 3) * 32;
  const int fr = lane & 15, g4 = lane >> 4;
  const int sr = lane >> 3, sc = lane & 7;

  size_t aoff[4];
  size_t boff[2];
#pragma unroll
  for (int st = 0; st < 4; ++st) {
    const int R = st * 64 + wave * 8 + sr;
    const int u = sc ^ (R & 7);
    aoff[st] = (size_t)(m0 + R) * 2048 + ((size_t)u << 3);   // hi region of X2
  }
#pragma unroll
  for (int st = 0; st < 2; ++st) {
    const int R = st * 64 + wave * 8 + sr;
    const int u = sc ^ (R & 7);
    boff[st] = (size_t)(n0 + R) * 1024 + ((size_t)u << 3);
  }
  int aro[2][8], bro[2][2];     // [kk][i]
#pragma unroll
  for (int i = 0; i < 8; ++i) {
    const int Ra = wm + i * 16 + fr;
    aro[0][i] = Ra * 64 + ((g4 ^ (Ra & 7)) << 3);
    aro[1][i] = Ra * 64 + (((4 | g4) ^ (Ra & 7)) << 3);
  }
#pragma unroll
  for (int j = 0; j < 2; ++j) {
    const int Rb = wn + j * 16 + fr;
    bro[0][j] = Rb * 64 + ((g4 ^ (Rb & 7)) << 3);
    bro[1][j] = Rb * 64 + (((4 | g4) ^ (Rb & 7)) << 3);
  }

  f32x4 acc[8][2];
#pragma unroll
  for (int i = 0; i < 8; ++i)
#pragma unroll
    for (int j = 0; j < 2; ++j) acc[i][j] = (f32x4){0.f, 0.f, 0.f, 0.f};

#define NRM_STAGE(kt, slot) do {                                      \
    const size_t kof = (size_t)(kt) * 64;                             \
    _Float16* sb_ = smem + (slot) * 24576;                            \
    gld_lds16(X2 + aoff[0] + kof, sb_ + 0 * 4096 + wave * 512);       \
    gld_lds16(X2 + aoff[1] + kof, sb_ + 1 * 4096 + wave * 512);       \
    gld_lds16(X2 + aoff[2] + kof, sb_ + 2 * 4096 + wave * 512);       \
    gld_lds16(X2 + aoff[3] + kof, sb_ + 3 * 4096 + wave * 512);       \
    gld_lds16(Wh + boff[0] + kof, sb_ + 16384 + 0 * 4096 + wave * 512); \
    gld_lds16(Wh + boff[1] + kof, sb_ + 16384 + 1 * 4096 + wave * 512); \
  } while (0)

  NRM_STAGE(0, 0);
  NRM_STAGE(1, 1);
  int slot = 0;
  for (int kt = 0; kt < 16; ++kt) {
    if (kt < 15) asm volatile("s_waitcnt vmcnt(6)" ::: "memory");
    else         asm volatile("s_waitcnt vmcnt(0)" ::: "memory");
    __builtin_amdgcn_s_barrier();
    asm volatile("" ::: "memory");
    if (kt + 2 < 16) {
      int s2 = slot + 2; if (s2 >= 3) s2 -= 3;
      NRM_STAGE(kt + 2, s2);
    }
    const _Float16* A  = smem + slot * 24576;
    const _Float16* Bm = A + 16384;
    half8 b0[2], b1[2];
#pragma unroll
    for (int j = 0; j < 2; ++j) {
      b0[j] = *(const half8*)&Bm[bro[0][j]];
      b1[j] = *(const half8*)&Bm[bro[1][j]];
    }
#pragma unroll
    for (int ph = 0; ph < 4; ++ph) {
      const int i0 = ph * 2;
      half8 a00 = *(const half8*)&A[aro[0][i0]];
      half8 a01 = *(const half8*)&A[aro[1][i0]];
      half8 a10 = *(const half8*)&A[aro[0][i0 + 1]];
      half8 a11 = *(const half8*)&A[aro[1][i0 + 1]];
      __builtin_amdgcn_s_setprio(1);
#pragma unroll
      for (int j = 0; j < 2; ++j) {
        acc[i0][j]     = __builtin_amdgcn_mfma_f32_16x16x32_f16(a00, b0[j], acc[i0][j], 0, 0, 0);
        acc[i0][j]     = __builtin_amdgcn_mfma_f32_16x16x32_f16(a01, b1[j], acc[i0][j], 0, 0, 0);
        acc[i0 + 1][j] = __builtin_amdgcn_mfma_f32_16x16x32_f16(a10, b0[j], acc[i0 + 1][j], 0, 0, 0);
        acc[i0 + 1][j] = __builtin_amdgcn_mfma_f32_16x16x32_f16(a11, b1[j], acc[i0 + 1][j], 0, 0, 0);
      }
      __builtin_amdgcn_s_setprio(0);
    }
    __builtin_amdgcn_sched_barrier(0);
    slot = (slot == 2) ? 0 : slot + 1;
  }

  // epilogue: vsum = sum_j (q_j + bias_j)^2, block-reduce 4 N-groups via LDS
  float bias_j[2];
#pragma unroll
  for (int j = 0; j < 2; ++j) {
    const int n = n0 + wn + 16 * j + fr;
    bias_j[j] = (n < Dd) ? bq[n] : bk[n - Dd];
  }
  float* scratch = (float*)smem;
  const int quad = g4;
#pragma unroll
  for (int i = 0; i < 8; ++i) {
#pragma unroll
    for (int r = 0; r < 4; ++r) {
      const int row = wm + 16 * i + quad * 4 + r;
      float vsum = 0.f;
#pragma unroll
      for (int j = 0; j < 2; ++j) {
        float q = acc[i][j][r] + bias_j[j];
        vsum += q * q;
      }
      vsum += __shfl_xor(vsum, 1);
      vsum += __shfl_xor(vsum, 2);
      vsum += __shfl_xor(vsum, 4);
      vsum += __shfl_xor(vsum, 8);
      if (fr == 0) scratch[row * 4 + (wave & 3)] = vsum;
    }
  }
  __syncthreads();
  if (tid < 256) {
    float v = scratch[tid * 4] + scratch[tid * 4 + 1] +
              scratch[tid * 4 + 2] + scratch[tid * 4 + 3];
    pn[(size_t)(logical & 15) * Mm + (m0 + tid)] = v;
  }
}

// ---------------- final cos / p / b (thread per row) -------------------------
__global__ void cos_final(const float* __restrict__ pd, const float* __restrict__ pn,
                          const float* __restrict__ a_u, const float* __restrict__ a_v,
                          const float* __restrict__ cptr,
                          float* __restrict__ p_out, float* __restrict__ b_out) {
  const int s = blockIdx.x * 256 + threadIdx.x;
  if ((s & (Ss - 1)) == 0) { p_out[s] = 1.0f; b_out[s] = 1.0f; return; }
  float dot = a_u[s - 1] + a_v[s] + *cptr;
#pragma unroll
  for (int sl = 0; sl < 8; ++sl) dot += pd[(size_t)sl * Mm + s];
  float nq = 0.f, nk = 0.f;
#pragma unroll
  for (int sl = 0; sl < 8; ++sl) nq += pn[(size_t)sl * Mm + s];
#pragma unroll
  for (int sl = 8; sl < 16; ++sl) nk += pn[(size_t)sl * Mm + (s - 1)];
  float denom = fmaxf(sqrtf(nq), 1e-8f) * fmaxf(sqrtf(nk), 1e-8f);
  float cs = dot / denom;
  float p = 0.5f * (1.0f - cs);
  p_out[s] = p;
  b_out[s] = (p >= 0.5f) ? 1.0f : 0.0f;
}

// ---------------- per-batch stable scan of flags (1024 thr, 4 chunks) --------
__global__ __launch_bounds__(1024)
void scan_flags(const float* __restrict__ b_out,
                int* __restrict__ sel, int* __restrict__ counts) {
  const int b = blockIdx.x;
  const int tid = threadIdx.x;
  const int lane = tid & 63;
  const int w = tid >> 6;          // 16 waves
  __shared__ int wtot[16];
  float fv[4];
#pragma unroll
  for (int c = 0; c < 4; ++c) fv[c] = b_out[b * Ss + c * 1024 + tid];
  int running = 0;
#pragma unroll
  for (int c = 0; c < 4; ++c) {
    const bool f = fv[c] != 0.0f;
    unsigned long long m = __ballot(f);
    int pre = __popcll(m & ((1ull << lane) - 1ull));
    if (lane == 0) wtot[w] = __popcll(m);
    __syncthreads();
    int woff = 0, tot = 0;
#pragma unroll
    for (int ww = 0; ww < 16; ++ww) {
      int t = wtot[ww];
      if (ww < w) woff += t;
      tot += t;
    }
    if (f) sel[b * Ss + running + woff + pre] = c * 1024 + tid;
    running += tot;
    __syncthreads();
  }
  if (tid == 0) counts[b] = running;
}

// ---------------- gather selected rows / zero-fill ---------------------------
__global__ void write_out(const float* __restrict__ x, const int* __restrict__ sel,
                          const int* __restrict__ counts, float* __restrict__ out) {
  const int blk = blockIdx.x;
  const int b = blk >> 12;
  const int r = blk & (Ss - 1);
  const int tid = threadIdx.x;
  float4 v = {0.f, 0.f, 0.f, 0.f};
  if (r < counts[b]) {
    const int src = sel[b * Ss + r];
    v = *(const float4*)&x[((size_t)b * Ss + src) * Dd + tid * 4];
  }
  *(float4*)&out[(size_t)blk * Dd + tid * 4] = v;
}

extern "C" void kernel_launch(void* const* d_in, const int* in_sizes, int n_in,
                              void* d_out, int out_size, void* d_ws, size_t ws_size,
                              hipStream_t stream) {
  const float* x  = (const float*)d_in[0];
  const float* Wq = (const float*)d_in[1];
  const float* bq = (const float*)d_in[2];
  const float* Wk = (const float*)d_in[3];
  const float* bk = (const float*)d_in[4];
  float* out = (float*)d_out;

  uint8_t* w = (uint8_t*)d_ws;
  _Float16* X2 = (_Float16*)w; w += (size_t)Mm * 2048 * 2;       // 128 MB
  float*    Gp = (float*)w;    w += (size_t)4 * Dd * Dd * 4;     // 16 MB
  _Float16* G2 = (_Float16*)w; w += (size_t)Dd * 2048 * 2;       // 4 MB
  _Float16* Wh = (_Float16*)w; w += (size_t)2 * Dd * Dd * 2;     // 4 MB
  float* pd = (float*)w;       w += (size_t)8 * Mm * 4;          // 1 MB
  float* pn = (float*)w;       w += (size_t)16 * Mm * 4;         // 2 MB
  float* a_u = (float*)w;      w += (size_t)Mm * 4;
  float* a_v = (float*)w;      w += (size_t)Mm * 4;
  float* up  = (float*)w;      w += (size_t)4 * Dd * 4;
  float* vp  = (float*)w;      w += (size_t)4 * Dd * 4;
  float* cpt = (float*)w;      w += 64;
  int*   sel = (int*)w;        w += (size_t)Mm * 4;
  int*   counts = (int*)w;     w += 64;

  float* p_out = out + (size_t)Mm * Dd;
  float* b_out = p_out + Mm;

  // prep (independent of X): G partials, u/v partials, c
  gemm_g_part<<<dim3(16, 16, 4), 256, 0, stream>>>(Wq, Wk, Gp);
  uvc_part<<<33, 256, 0, stream>>>(Wq, Wk, bq, bk, up, vp, cpt);
  // splits
  split_x<<<Mm / 4, 256, 0, stream>>>(x, up, vp, X2, a_u, a_v);
  split_w3<<<dim3((Dd * Dd / 4) / 256, 3), 256, 0, stream>>>(Gp, Wq, Wk, G2, Wh);
  // pipelined MFMA passes
  gemm_norm<<<dim3(16, Mm / 256), 512, 0, stream>>>(X2, Wh, bq, bk, pn);
  gemm_dot<<<dim3(8, Mm / 256), 512, 0, stream>>>(X2, G2, x, pd);
  // epilogue chain
  cos_final<<<Mm / 256, 256, 0, stream>>>(pd, pn, a_u, a_v, cpt, p_out, b_out);
  scan_flags<<<Bb, 1024, 0, stream>>>(b_out, sel, counts);
  write_out<<<Mm, 256, 0, stream>>>(x, sel, counts, out);
}